// Round 4
// baseline (967.670 us; speedup 1.0000x reference)
//
#include <hip/hip_runtime.h>
#include <cstdint>
#include <cstddef>

// Problem constants
#define BB   4
#define TT   1024
#define CC   1024
#define HH   16
#define HSS  64
#define NNtok 4096            // B*T
#define EPSGN 0.00064f

typedef unsigned short bf16u;
typedef __attribute__((ext_vector_type(8))) short short8;
typedef __attribute__((ext_vector_type(4))) float f32x4;
#define SLOT 4194304ull       // elements per 8MiB bf16 slot (= NNtok*CC)

__device__ __forceinline__ float bf2f(bf16u u){
  union { unsigned int i; float f; } cv; cv.i = ((unsigned int)u) << 16; return cv.f;
}
__device__ __forceinline__ unsigned short f2bfbits(unsigned int x){
  return (unsigned short)((x + 0x7fffu + ((x >> 16) & 1u)) >> 16);   // RNE
}
__device__ __forceinline__ bf16u f2bf(float f){
  union { float f; unsigned int i; } cv; cv.f = f;
  return f2bfbits(cv.i);
}
__device__ __forceinline__ void ld4bf(const bf16u* p, float* o){
  ushort4 u = *reinterpret_cast<const ushort4*>(p);
  o[0]=bf2f(u.x); o[1]=bf2f(u.y); o[2]=bf2f(u.z); o[3]=bf2f(u.w);
}
__device__ __forceinline__ void st4bf(bf16u* p, const float* v){
  ushort4 u; u.x=f2bf(v[0]); u.y=f2bf(v[1]); u.z=f2bf(v[2]); u.w=f2bf(v[3]);
  *reinterpret_cast<ushort4*>(p) = u;
}
__device__ __forceinline__ unsigned short f2h(float f){
  union { _Float16 h; unsigned short s; } c; c.h = (_Float16)f; return c.s;
}
__device__ __forceinline__ void st4h(bf16u* p, const float* v){
  ushort4 u; u.x=f2h(v[0]); u.y=f2h(v[1]); u.z=f2h(v[2]); u.w=f2h(v[3]);
  *reinterpret_cast<ushort4*>(p) = u;
}
__device__ __forceinline__ void ld4f(const float* p, float* o){
  float4 v = *reinterpret_cast<const float4*>(p);
  o[0]=v.x; o[1]=v.y; o[2]=v.z; o[3]=v.w;
}
__device__ __forceinline__ float sigm(float x){ return 1.f / (1.f + expf(-x)); }

// unpack helpers for a uint holding two bf16 (lo,hi) or two f16 (lo,hi)
__device__ __forceinline__ float bflo(unsigned int u){
  union { unsigned int i; float f; } c; c.i = u << 16; return c.f;
}
__device__ __forceinline__ float bfhi(unsigned int u){
  union { unsigned int i; float f; } c; c.i = u & 0xffff0000u; return c.f;
}
__device__ __forceinline__ float hlo(unsigned int u){
  union { unsigned short s; _Float16 h; } c; c.s = (unsigned short)(u & 0xffffu); return (float)c.h;
}
__device__ __forceinline__ float hhi(unsigned int u){
  union { unsigned short s; _Float16 h; } c; c.s = (unsigned short)(u >> 16); return (float)c.h;
}

// 16-lane sum via DPP (groups must be 16-lane aligned). 4 plain-VALU adds,
// no ds_bpermute / lgkmcnt waits on the critical path.
template<int CTRL>
__device__ __forceinline__ float dpp_add(float v){
  union { float f; int i; } a, b;
  a.f = v;
  b.i = __builtin_amdgcn_update_dpp(a.i, a.i, CTRL, 0xF, 0xF, false);
  return v + b.f;
}
__device__ __forceinline__ float red16(float v){
  v = dpp_add<0xB1>(v);    // quad_perm [1,0,3,2]  (xor 1)
  v = dpp_add<0x4E>(v);    // quad_perm [2,3,0,1]  (xor 2)
  v = dpp_add<0x124>(v);   // row_ror:4
  v = dpp_add<0x128>(v);   // row_ror:8
  return v;
}
// 32-lane sum, result in all 32 lanes of each half-wave. After red16 every
// lane of 16-row r holds sum_r. v_permlane16_swap_b32 on two DISTINCT
// registers holding identical copies exchanges complementary 16-rows
// between them, so x'+y' = rowpair sum in every lane (convention-agnostic).
// CRITICAL: rounds 1/3 failed (4.3e-2) because the register allocator
// coalesced x and y (same SSA value) into ONE phys VGPR -> self-swap ->
// 2*(wrong half). The empty asm launders y into a fresh vreg; both are
// live into the swap asm => interference => distinct phys regs guaranteed.
// Pure VALU: no DS pipe, no lgkmcnt (round-2's ds_swizzle variant flipped
// wrong under warm-cache replay).
__device__ __forceinline__ float red32(float v){
  v = red16(v);
  union { float f; int i; } x, y;
  x.f = v; y.f = v;
  asm volatile("" : "+v"(y.i));   // distinct-vreg launder
  asm volatile("v_permlane16_swap_b32 %0, %1" : "+v"(x.i), "+v"(y.i));
  return x.f + y.f;
}

// ---------------------------------------------------------------------------
// mix = x + (x[t-1]-x[t])*time_maa_x  (x[-1]=0), stored bf16
// ---------------------------------------------------------------------------
__global__ __launch_bounds__(256) void k_prep(const float* __restrict__ x,
                                              const float* __restrict__ tmx,
                                              bf16u* __restrict__ MIX){
  int e = (blockIdx.x * 256 + threadIdx.x) * 4;
  int n = e >> 10;
  int c = e & (CC - 1);
  int t = n & (TT - 1);
  float xf[4]; ld4f(x + e, xf);
  float pf[4] = {0.f, 0.f, 0.f, 0.f};
  if (t > 0) ld4f(x + e - CC, pf);
  float tm[4]; ld4f(tmx + c, tm);
  float mv[4];
  #pragma unroll
  for (int i = 0; i < 4; ++i) mv[i] = xf[i] + (pf[i] - xf[i]) * tm[i];
  st4bf(MIX + e, mv);
}

// ---------------------------------------------------------------------------
// MFMA NT GEMM: OUT[M,Nd] = X[M,K](bf16) @ W[Nd,K]^T, W as up to 3 row-blocks
// (f32). tanh on cols < act_n. OB: bf16 out else f32. 128x128, BK=32.
// ---------------------------------------------------------------------------
template<bool OB>
__global__ __launch_bounds__(256) void k_gemm_mfma(const bf16u* __restrict__ X,
                                                   const float* __restrict__ Wa,
                                                   const float* __restrict__ Wb,
                                                   const float* __restrict__ Wc,
                                                   int na, int nab,
                                                   void* __restrict__ OUTv,
                                                   int Nd, int Kd, int act_n){
  __shared__ short As[128 * 40];
  __shared__ short Bs[128 * 40];
  const int tid  = threadIdx.x;
  const int lane = tid & 63;
  const int wv   = tid >> 6;
  const int wm   = wv >> 1, wn = wv & 1;
  const int bn0  = blockIdx.x * 128;
  const int bm0  = blockIdx.y * 128;
  const int l15  = lane & 15;
  const int quad = lane >> 4;

  f32x4 acc[4][4];
  #pragma unroll
  for (int mi = 0; mi < 4; ++mi)
    #pragma unroll
    for (int ni = 0; ni < 4; ++ni)
      #pragma unroll
      for (int rg = 0; rg < 4; ++rg) acc[mi][ni][rg] = 0.f;

  const int r    = tid >> 1;
  const int half = (tid & 1) * 16;

  int rr = bn0 + r;
  const float* wsrc = nullptr;
  if (rr < na)        wsrc = Wa + (size_t)rr * Kd;
  else if (rr < nab)  wsrc = Wb + (size_t)(rr - na) * Kd;
  else if (rr < Nd)   wsrc = Wc + (size_t)(rr - nab) * Kd;
  const bf16u* xsrc = X + (size_t)(bm0 + r) * Kd;

  for (int k0 = 0; k0 < Kd; k0 += 32){
    uint4 xa = *(const uint4*)(xsrc + k0 + half);
    uint4 xb = *(const uint4*)(xsrc + k0 + half + 8);
    uint4 w0 = make_uint4(0,0,0,0), w1 = w0, w2 = w0, w3 = w0;
    if (wsrc){
      w0 = *(const uint4*)(wsrc + k0 + half);
      w1 = *(const uint4*)(wsrc + k0 + half + 4);
      w2 = *(const uint4*)(wsrc + k0 + half + 8);
      w3 = *(const uint4*)(wsrc + k0 + half + 12);
    }
    union { unsigned short s[8]; uint4 v; } p0, p1;
    p0.s[0]=f2bfbits(w0.x); p0.s[1]=f2bfbits(w0.y); p0.s[2]=f2bfbits(w0.z); p0.s[3]=f2bfbits(w0.w);
    p0.s[4]=f2bfbits(w1.x); p0.s[5]=f2bfbits(w1.y); p0.s[6]=f2bfbits(w1.z); p0.s[7]=f2bfbits(w1.w);
    p1.s[0]=f2bfbits(w2.x); p1.s[1]=f2bfbits(w2.y); p1.s[2]=f2bfbits(w2.z); p1.s[3]=f2bfbits(w2.w);
    p1.s[4]=f2bfbits(w3.x); p1.s[5]=f2bfbits(w3.y); p1.s[6]=f2bfbits(w3.z); p1.s[7]=f2bfbits(w3.w);

    *(uint4*)&As[r * 40 + half]     = xa;
    *(uint4*)&As[r * 40 + half + 8] = xb;
    *(uint4*)&Bs[r * 40 + half]     = p0.v;
    *(uint4*)&Bs[r * 40 + half + 8] = p1.v;
    __syncthreads();

    short8 af[4], bfg[4];
    #pragma unroll
    for (int mi = 0; mi < 4; ++mi)
      af[mi] = *(const short8*)&As[(wm*64 + mi*16 + l15) * 40 + quad*8];
    #pragma unroll
    for (int ni = 0; ni < 4; ++ni)
      bfg[ni] = *(const short8*)&Bs[(wn*64 + ni*16 + l15) * 40 + quad*8];
    #pragma unroll
    for (int mi = 0; mi < 4; ++mi)
      #pragma unroll
      for (int ni = 0; ni < 4; ++ni)
        acc[mi][ni] = __builtin_amdgcn_mfma_f32_16x16x32_bf16(af[mi], bfg[ni], acc[mi][ni], 0, 0, 0);
    __syncthreads();
  }

  #pragma unroll
  for (int mi = 0; mi < 4; ++mi){
    #pragma unroll
    for (int ni = 0; ni < 4; ++ni){
      int col = bn0 + wn*64 + ni*16 + l15;
      if (col >= Nd) continue;
      #pragma unroll
      for (int rg = 0; rg < 4; ++rg){
        int row = bm0 + wm*64 + mi*16 + quad*4 + rg;
        float v = acc[mi][ni][rg];
        if (col < act_n) v = tanhf(v);
        if (OB) ((bf16u*)OUTv)[(size_t)row * Nd + col] = f2bf(v);
        else    ((float*)OUTv)[(size_t)row * Nd + col] = v;
      }
    }
  }
}

// ---------------------------------------------------------------------------
// MFMA NN GEMM: OUT[M, CC] = A[M, KD](bf16, row stride lda) @ B[KD, CC](f32).
// EP=0: plain bf16 store. EP=1: token-shift epilogue.
// ---------------------------------------------------------------------------
template<int KD, int EP>
__global__ __launch_bounds__(256) void k_gemm_nn(const bf16u* __restrict__ A, int lda,
                                                 const float* __restrict__ B,
                                                 bf16u* __restrict__ OUT,
                                                 const float* __restrict__ x,
                                                 const float* __restrict__ tma_g){
  __shared__ short As[128 * (KD + 8)];
  __shared__ short Bs[128 * (KD + 8)];
  const int tid  = threadIdx.x;
  const int lane = tid & 63;
  const int wv   = tid >> 6;
  const int wm   = wv >> 1, wn = wv & 1;
  const int bn0  = blockIdx.x * 128;
  const int bm0  = blockIdx.y * 128;
  const int l15  = lane & 15;
  const int quad = lane >> 4;

  for (int idx = tid; idx < 128 * (KD / 8); idx += 256){
    int r  = idx / (KD / 8);
    int kc = (idx % (KD / 8)) * 8;
    *(uint4*)&As[r * (KD + 8) + kc] =
        *(const uint4*)(A + (size_t)(bm0 + r) * lda + kc);
  }
  for (int idx = tid; idx < KD * 128; idx += 256){
    int k = idx >> 7, c = idx & 127;
    Bs[c * (KD + 8) + k] = (short)f2bf(B[(size_t)k * CC + bn0 + c]);
  }
  __syncthreads();

  f32x4 acc[4][4];
  #pragma unroll
  for (int mi = 0; mi < 4; ++mi)
    #pragma unroll
    for (int ni = 0; ni < 4; ++ni)
      #pragma unroll
      for (int rg = 0; rg < 4; ++rg) acc[mi][ni][rg] = 0.f;

  #pragma unroll
  for (int kk = 0; kk < KD; kk += 32){
    short8 af[4], bfg[4];
    #pragma unroll
    for (int mi = 0; mi < 4; ++mi)
      af[mi] = *(const short8*)&As[(wm*64 + mi*16 + l15) * (KD + 8) + kk + quad*8];
    #pragma unroll
    for (int ni = 0; ni < 4; ++ni)
      bfg[ni] = *(const short8*)&Bs[(wn*64 + ni*16 + l15) * (KD + 8) + kk + quad*8];
    #pragma unroll
    for (int mi = 0; mi < 4; ++mi)
      #pragma unroll
      for (int ni = 0; ni < 4; ++ni)
        acc[mi][ni] = __builtin_amdgcn_mfma_f32_16x16x32_bf16(af[mi], bfg[ni], acc[mi][ni], 0, 0, 0);
  }

  #pragma unroll
  for (int mi = 0; mi < 4; ++mi){
    #pragma unroll
    for (int ni = 0; ni < 4; ++ni){
      int col = bn0 + wn*64 + ni*16 + l15;
      float tm = (EP == 1) ? tma_g[col] : 0.f;
      #pragma unroll
      for (int rg = 0; rg < 4; ++rg){
        int row = bm0 + wm*64 + mi*16 + quad*4 + rg;
        float v = acc[mi][ni][rg];
        if (EP == 1){
          float xv = x[(size_t)row * CC + col];
          float xp = ((row & (TT - 1)) == 0) ? 0.f : x[(size_t)row * CC + col - CC];
          v = xv + (xp - xv) * (v + tm);
        }
        OUT[(size_t)row * CC + col] = f2bf(v);
      }
    }
  }
}

// ---------------------------------------------------------------------------
// Fused elementwise, tiled 4 tokens/block.
// UX stores -u = -exp(w) as f16. Self-normalizing representation: log-error
// of w_t = exp(-u) is u*eps_f16 (~u*5e-4), vanishing exactly where the
// recurrence horizon 1/(1-w_t)~1/u diverges. Validated by round-2's first
// correctness check (2.6e-3).
// ---------------------------------------------------------------------------
__global__ __launch_bounds__(256) void k_elem(bf16u* __restrict__ K0,
    const bf16u* __restrict__ P1, const bf16u* __restrict__ P2,
    const bf16u* __restrict__ W2A,
    const float* __restrict__ kw2, const float* __restrict__ aw2,
    const float* __restrict__ maw2, const float* __restrict__ mkw2,
    const float* __restrict__ td,  const float* __restrict__ taa,
    const float* __restrict__ tma, const float* __restrict__ tmk,
    bf16u* __restrict__ KKN, bf16u* __restrict__ Bb, bf16u* __restrict__ UX){
  int n0 = blockIdx.x * 4, tid = threadIdx.x;
  __shared__ float at_l[4][16], mat_l[4][16], kt_l[4][16], mkt_l[4][16];
  {
    int grp = tid >> 6, q = tid & 63, tt = q >> 4, j = q & 15;
    if (grp == 0)      at_l[tt][j]  = bf2f(P1[(size_t)(n0+tt)*96 + 64 + j]);
    else if (grp == 1) mat_l[tt][j] = bf2f(P1[(size_t)(n0+tt)*96 + 80 + j]);
    else if (grp == 2) kt_l[tt][j]  = bf2f(P2[(size_t)(n0+tt)*32 + j]);
    else               mkt_l[tt][j] = bf2f(P2[(size_t)(n0+tt)*32 + 16 + j]);
  }
  __syncthreads();
  int c = tid * 4;

  float kkk[4][4], aa[4][4], mam[4][4], mkm[4][4];
  #pragma unroll
  for (int tt = 0; tt < 4; ++tt)
    #pragma unroll
    for (int i = 0; i < 4; ++i){ kkk[tt][i]=0; aa[tt][i]=0; mam[tt][i]=0; mkm[tt][i]=0; }

  #pragma unroll 4
  for (int j = 0; j < 16; ++j){
    float wk[4], wa[4], wm[4], wq[4];
    ld4f(kw2  + (size_t)j*CC + c, wk);
    ld4f(aw2  + (size_t)j*CC + c, wa);
    ld4f(maw2 + (size_t)j*CC + c, wm);
    ld4f(mkw2 + (size_t)j*CC + c, wq);
    #pragma unroll
    for (int tt = 0; tt < 4; ++tt){
      float s1 = kt_l[tt][j], s2 = at_l[tt][j], s3 = mat_l[tt][j], s4 = mkt_l[tt][j];
      #pragma unroll
      for (int i = 0; i < 4; ++i){
        kkk[tt][i] += s1 * wk[i];
        aa[tt][i]  += s2 * wa[i];
        mam[tt][i] += s3 * wm[i];
        mkm[tt][i] += s4 * wq[i];
      }
    }
  }

  float td4[4], taa4[4], tma4[4], tmk4[4];
  ld4f(td + c, td4); ld4f(taa + c, taa4); ld4f(tma + c, tma4); ld4f(tmk + c, tmk4);

  for (int tt = 0; tt < 4; ++tt){
    size_t e = (size_t)(n0 + tt) * CC + c;
    float k0a[4]; ld4bf(K0 + e, k0a);
    float w2a[4]; ld4bf(W2A + e, w2a);

    float kkv[4];
    float ssq = 0.f;
    #pragma unroll
    for (int i = 0; i < 4; ++i){ kkv[i] = k0a[i] + kkk[tt][i]; ssq += kkv[i]*kkv[i]; }
    ssq = red16(ssq);
    float rinv = 1.f / fmaxf(sqrtf(ssq), 1e-12f);

    float kkn[4], outb[4], outkf[4], outw[4];
    #pragma unroll
    for (int i = 0; i < 4; ++i){
      float z  = td4[i] + w2a[i];
      float nz = -z;
      float sp = (nz > 15.f) ? nz : log1pf(expf(nz));
      float w  = -sp - 0.5f;               // <= -0.5
      float av  = sigm(taa4[i] + aa[tt][i]);
      float mav = sigm(tma4[i] + mam[tt][i]);
      float mkv = sigm(tmk4[i] + mkm[tt][i]);
      kkn[i]  = kkv[i] * rinv;
      outb[i] = -kkn[i] * av;
      outkf[i]= k0a[i] * (mav + av * (1.f - mav)) * expf(w * mkv);
      outw[i] = -expf(w);                  // -u in [-0.607, 0), stored f16
    }
    st4bf(KKN + e, kkn);
    st4bf(Bb  + e, outb);
    st4bf(K0  + e, outkf);
    st4h (UX  + e, outw);
  }
}

// ---------------------------------------------------------------------------
// Recurrence v9: 32 lanes/row x 2 cols/lane -> 2048 waves (2 waves/SIMD,
// 2x the TLP of v5's 1 wave/SIMD). red32 = red16 (DPP) + laundered
// v_permlane16_swap_b32 (pure VALU, distinct-reg guaranteed; see red32).
// Decay stored as -u (f16, self-normalizing); w_t = __expf(-u) in-loop.
// Blocks of the same (b,h) cluster onto one XCD (blockIdx % 8) for L2
// sharing of column data.
// ---------------------------------------------------------------------------
__global__ __launch_bounds__(256) void k_rec(const bf16u* __restrict__ Q,
                                             const bf16u* __restrict__ WT,
                                             const bf16u* __restrict__ KFt,
                                             const bf16u* __restrict__ Vt,
                                             const bf16u* __restrict__ Aa,
                                             const bf16u* __restrict__ Bv,
                                             bf16u* __restrict__ Y){
  const int p   = blockIdx.x;                 // 0..511
  const int g   = (p & 7) | ((p >> 6) << 3);  // (b,h) group 0..63, XCD-clustered
  const int oct = (p >> 3) & 7;               // row octet within the head
  const int b   = g >> 4;
  const int h   = g & 15;
  const int tid = threadIdx.x;
  const int l31 = tid & 31;
  const int i   = oct * 8 + (tid >> 5);       // state row 0..63 (one row / 32 lanes)
  const size_t colbase = (size_t)(b * TT) * CC + h * HSS + l31 * 2;
  const size_t rowbase = (size_t)(b * TT) * CC + h * HSS + i;

  float S0 = 0.f, S1 = 0.f;                   // state cols (2*l31, 2*l31+1) of row i
  float ypA = 0.f, ypB = 0.f, ypC = 0.f, ypD = 0.f;

  unsigned int qA,kA,aA,bA,wA; unsigned short vA;
  unsigned int qB,kB,aB,bB,wB; unsigned short vB;
  unsigned int qC,kC,aC,bC,wC; unsigned short vC;
  unsigned int qD,kD,aD,bD,wD; unsigned short vD;

#define KREC_LOAD(SFX, T_) do{ \
    size_t cb_ = colbase + (size_t)(T_) * CC; \
    q##SFX = *(const unsigned int*)(Q   + cb_); \
    k##SFX = *(const unsigned int*)(KFt + cb_); \
    a##SFX = *(const unsigned int*)(Aa  + cb_); \
    b##SFX = *(const unsigned int*)(Bv  + cb_); \
    w##SFX = *(const unsigned int*)(WT  + cb_); \
    v##SFX = Vt[rowbase + (size_t)(T_) * CC]; \
  }while(0)

#define KREC_STEP(SFX) do{ \
    float a0 = bflo(a##SFX), a1 = bfhi(a##SFX); \
    float w0 = __expf(hlo(w##SFX)), w1 = __expf(hhi(w##SFX)); \
    float k0 = bflo(k##SFX), k1 = bfhi(k##SFX); \
    float b0 = bflo(b##SFX), b1 = bfhi(b##SFX); \
    float q0 = bflo(q##SFX), q1 = bfhi(q##SFX); \
    float vi = bf2f(v##SFX); \
    float sa = fmaf(S1, a1, S0 * a0); \
    sa = red32(sa); \
    S0 = fmaf(S0, w0, fmaf(sa, b0, vi * k0)); \
    S1 = fmaf(S1, w1, fmaf(sa, b1, vi * k1)); \
    yp##SFX = fmaf(S1, q1, S0 * q0); \
  }while(0)

#define KREC_FLUSH(SFX, T_) do{ \
    float yp_ = red32(yp##SFX); \
    if (l31 == 0) Y[rowbase + (size_t)(T_) * CC] = f2bf(yp_); \
  }while(0)

  KREC_LOAD(A, 0); KREC_LOAD(B, 1); KREC_LOAD(C, 2); KREC_LOAD(D, 3);
  for (int t = 0; t < TT; t += 4){
    KREC_STEP(A);
    if (t) KREC_FLUSH(D, t - 1);
    if (t + 4 < TT) KREC_LOAD(A, t + 4);
    KREC_STEP(B);
    KREC_FLUSH(A, t);
    if (t + 5 < TT) KREC_LOAD(B, t + 5);
    KREC_STEP(C);
    KREC_FLUSH(B, t + 1);
    if (t + 6 < TT) KREC_LOAD(C, t + 6);
    KREC_STEP(D);
    KREC_FLUSH(C, t + 2);
    if (t + 7 < TT) KREC_LOAD(D, t + 7);
  }
  KREC_FLUSH(D, TT - 1);
#undef KREC_LOAD
#undef KREC_STEP
#undef KREC_FLUSH
}

// ---------------------------------------------------------------------------
// Post: GroupNorm + bonus (r.k*faaaa)v + precomputed gate GV -> YG (bf16)
// ---------------------------------------------------------------------------
__global__ __launch_bounds__(256) void k_post(const bf16u* __restrict__ Y,
                                              const bf16u* __restrict__ R,
                                              const bf16u* __restrict__ KFt,
                                              const bf16u* __restrict__ Vt,
                                              const bf16u* __restrict__ GV,
                                              const float* __restrict__ lnw,
                                              const float* __restrict__ lnb,
                                              const float* __restrict__ faaaa,
                                              bf16u* __restrict__ YG){
  int n = blockIdx.x, tid = threadIdx.x;
  int c = tid * 4;
  size_t e = (size_t)n * CC + c;

  float ya[4]; ld4bf(Y + e, ya);
  float s = ya[0] + ya[1] + ya[2] + ya[3];
  s = red16(s);
  float mu = s * (1.f / 64.f);
  float d[4], vs = 0.f;
  #pragma unroll
  for (int i = 0; i < 4; ++i){ d[i] = ya[i] - mu; vs += d[i] * d[i]; }
  vs = red16(vs);
  float rstd = rsqrtf(vs * (1.f / 64.f) + EPSGN);

  float r4[4], k4[4], va[4], fa4[4];
  ld4bf(R + e, r4); ld4bf(KFt + e, k4); ld4bf(Vt + e, va);
  ld4f(faaaa + c, fa4);
  float rk = r4[0]*k4[0]*fa4[0] + r4[1]*k4[1]*fa4[1] + r4[2]*k4[2]*fa4[2] + r4[3]*k4[3]*fa4[3];
  rk = red16(rk);

  float lw4[4], lb4[4];
  ld4f(lnw + c, lw4); ld4f(lnb + c, lb4);
  float g[4]; ld4bf(GV + e, g);
  float o[4];
  #pragma unroll
  for (int i = 0; i < 4; ++i){
    float yn = d[i] * rstd * lw4[i] + lb4[i] + rk * va[i];
    o[i] = yn * g[i];
  }
  st4bf(YG + e, o);
}

// ---------------------------------------------------------------------------
extern "C" void kernel_launch(void* const* d_in, const int* in_sizes, int n_in,
                              void* d_out, int out_size, void* d_ws, size_t ws_size,
                              hipStream_t stream){
  (void)in_sizes; (void)n_in; (void)out_size; (void)ws_size;
  const float* x        = (const float*)d_in[0];
  const float* tmx      = (const float*)d_in[1];
  const float* tmaa     = (const float*)d_in[2];
  const float* maa_w1   = (const float*)d_in[3];
  const float* maa_w2   = (const float*)d_in[4];
  const float* decay_w1 = (const float*)d_in[5];
  const float* decay_w2 = (const float*)d_in[6];
  const float* aaa_w1   = (const float*)d_in[7];
  const float* aaa_w2   = (const float*)d_in[8];
  const float* kkk_w1   = (const float*)d_in[9];
  const float* kkk_w2   = (const float*)d_in[10];
  const float* gate_w1  = (const float*)d_in[11];
  const float* gate_w2  = (const float*)d_in[12];
  const float* ma_w1    = (const float*)d_in[13];
  const float* ma_w2    = (const float*)d_in[14];
  const float* mk_w1    = (const float*)d_in[15];
  const float* mk_w2    = (const float*)d_in[16];
  const float* t_decay  = (const float*)d_in[17];
  const float* t_faaaa  = (const float*)d_in[18];
  const float* t_aaaaa  = (const float*)d_in[19];
  const float* t_misc_a = (const float*)d_in[20];
  const float* t_misc_k = (const float*)d_in[21];
  const float* Wr       = (const float*)d_in[22];
  const float* Wk       = (const float*)d_in[23];
  const float* Wv       = (const float*)d_in[24];
  const float* Wo       = (const float*)d_in[25];
  const float* ln_w     = (const float*)d_in[26];
  const float* ln_b     = (const float*)d_in[27];

  // Slot map (8MiB bf16 each), 56 MiB + ~3 MiB smalls:
  // S0: MIX -> X0 -> KKN -> YG | S1: X1 -> Bb -> GV | S2: X2 -> UX(-u f16)
  // S3: X3 -> W2A -> Yb | S4: R | S5: K0 -> KF | S6: V
  bf16u* bw  = (bf16u*)d_ws;
  bf16u* MIX = bw + 0*SLOT;
  bf16u* X0  = bw + 0*SLOT;
  bf16u* KKN = bw + 0*SLOT;
  bf16u* YG  = bw + 0*SLOT;
  bf16u* X1  = bw + 1*SLOT;
  bf16u* Bb  = bw + 1*SLOT;
  bf16u* GV  = bw + 1*SLOT;
  bf16u* X2  = bw + 2*SLOT;
  bf16u* UX  = bw + 2*SLOT;
  bf16u* X3  = bw + 3*SLOT;
  bf16u* W2A = bw + 3*SLOT;
  bf16u* Yb  = bw + 3*SLOT;
  bf16u* R   = bw + 4*SLOT;
  bf16u* K0  = bw + 5*SLOT;   // becomes KF
  bf16u* V   = bw + 6*SLOT;
  char*  wsb = (char*)d_ws;
  bf16u* LO  = (bf16u*)(wsb + (56ull<<20));   // [N,128] bf16, 1 MiB
  bf16u* GT  = (bf16u*)(wsb + (57ull<<20));   // [N,128] bf16, 1 MiB
  bf16u* P1  = (bf16u*)(wsb + (58ull<<20));   // [N,96]  bf16 (dt|at|ma)
  bf16u* P2  = (bf16u*)(wsb + (58ull<<20) + (768ull<<10)); // [N,32] bf16

  // 1. mix
  k_prep<<<4096, 256, 0, stream>>>(x, tmx, MIX);
  // 2. lo = tanh(mix @ maa_w1^T) [N,128] bf16
  k_gemm_mfma<true><<<dim3(1,32),256,0,stream>>>(MIX, maa_w1, maa_w1, maa_w1,
                                                 128, 128, LO, 128, CC, 128);
  // 3. xm[g] = x + xx*(lo_g @ maa_w2_g + tmaa_g)   (NN GEMM + fused epilogue)
  bf16u* XMs[4] = {X0, X1, X2, X3};
  for (int g = 0; g < 4; ++g)
    k_gemm_nn<32,1><<<dim3(8,32),256,0,stream>>>(LO + g*32, 128,
                                                 maa_w2 + (size_t)g*32*CC,
                                                 XMs[g], x, tmaa + (size_t)g*CC);
  // 4. big projections (bf16 out)
  k_gemm_mfma<true><<<dim3(8,32),256,0,stream>>>(X0, Wr, Wr, Wr, CC, CC, R,  CC, CC, 0);
  k_gemm_mfma<true><<<dim3(8,32),256,0,stream>>>(X2, Wk, Wk, Wk, CC, CC, K0, CC, CC, 0);
  k_gemm_mfma<true><<<dim3(8,32),256,0,stream>>>(X3, Wv, Wv, Wv, CC, CC, V,  CC, CC, 0);
  // 5. first-stage LoRA projections (bf16 out)
  k_gemm_mfma<true><<<dim3(1,32),256,0,stream>>>(X0, gate_w1, gate_w1, gate_w1,
                                                 128, 128, GT, 128, CC, 128);
  k_gemm_mfma<true><<<dim3(1,32),256,0,stream>>>(X1, decay_w1, aaa_w1, ma_w1,
                                                 64, 80, P1, 96, CC, 64);
  k_gemm_mfma<true><<<dim3(1,32),256,0,stream>>>(X2, kkk_w1, mk_w1, mk_w1,
                                                 16, 32, P2, 32, CC, 16);
  // 6. decay second-stage projection: W2A = P1[:, :64] @ decay_w2  -> S3
  k_gemm_nn<64,0><<<dim3(8,32),256,0,stream>>>(P1, 96, decay_w2, W2A, nullptr, nullptr);
  // 7. fused elementwise (4 tokens/block); UX holds -u = -exp(w) as f16
  k_elem<<<1024, 256, 0, stream>>>(K0, P1, P2, W2A,
                                   kkk_w2, aaa_w2, ma_w2, mk_w2,
                                   t_decay, t_aaaaa, t_misc_a, t_misc_k,
                                   KKN, Bb, UX);
  // 8. delta-rule recurrence (v9: 512 blocks, 2 waves/SIMD, VALU-only reduce)
  k_rec<<<512, 256, 0, stream>>>(R, UX, K0, V, KKN, Bb, Yb);
  // 9. gate second-stage: GV = GT @ gate_w2 -> S1 (Bb dead after k_rec)
  k_gemm_nn<128,0><<<dim3(8,32),256,0,stream>>>(GT, 128, gate_w2, GV, nullptr, nullptr);
  // 10. groupnorm + bonus + gate
  k_post<<<4096, 256, 0, stream>>>(Yb, R, K0, V, GV, ln_w, ln_b, t_faaaa, YG);
  // 11. out = yg @ Wo^T -> f32
  k_gemm_mfma<false><<<dim3(8,32),256,0,stream>>>(YG, Wo, Wo, Wo, CC, CC, d_out, CC, CC, 0);
}